// Round 1
// baseline (285.948 us; speedup 1.0000x reference)
//
#include <hip/hip_runtime.h>
#include <hip/hip_bf16.h>

#define NB 16
#define NA 1614
#define NBP (NB * 196 * 128)   // p1 slab stride = 401408

typedef __bf16 bf16x8 __attribute__((ext_vector_type(8)));
typedef float f32x4 __attribute__((ext_vector_type(4)));

__device__ __forceinline__ unsigned short f2bf(float v) {
  unsigned u = __float_as_uint(v);
  unsigned r = (u + 0x7FFFu + ((u >> 16) & 1u)) >> 16;
  return (unsigned short)r;
}
__device__ __forceinline__ float bf2f(unsigned short s) {
  return __uint_as_float(((unsigned)s) << 16);
}

// ---------------- prep (fused): blocks [0,1024) transpose+split rpn -> aT; rest -> wT ------
// aT layout: [chunk = b*64 + ic32grp][pos196][ic32] hi/lo, written fully coalesced (pos-major).
__global__ __launch_bounds__(256)
void prep(const float* __restrict__ w, const float* __restrict__ in,
          unsigned short* __restrict__ wTh, unsigned short* __restrict__ wTl,
          unsigned short* __restrict__ aTh, unsigned short* __restrict__ aTl) {
  __shared__ float s[32 * 201];
  const int bid = blockIdx.x;
  if (bid < 1024) {
    const int chunk = bid & 63, b = bid >> 6;
    const float* src = in + ((size_t)b * 2048 + chunk * 32) * 196;
#pragma unroll
    for (int r = 0; r < 7; r++) {
      int e = threadIdx.x + 256 * r;
      if (e < 1568) {
        int ic = e / 49, f = e - ic * 49;
        float4 v = ((const float4*)(src + (size_t)ic * 196))[f];
        float* d = s + ic * 201 + f * 4;
        d[0] = v.x; d[1] = v.y; d[2] = v.z; d[3] = v.w;
      }
    }
    __syncthreads();
    unsigned short* oh = aTh + (size_t)bid * (196 * 32);
    unsigned short* ol = aTl + (size_t)bid * (196 * 32);
#pragma unroll
    for (int r = 0; r < 4; r++) {
      int e = threadIdx.x + 256 * r;   // uint4 units; e = pos*4 + part -> contiguous writes
      if (e < 784) {
        int pos = e >> 2, part = e & 3;
        unsigned short hv[8], lv[8];
#pragma unroll
        for (int j = 0; j < 8; j++) {
          float v = s[(part * 8 + j) * 201 + pos];
          unsigned short h = f2bf(v);
          hv[j] = h;
          lv[j] = f2bf(v - bf2f(h));
        }
        ((uint4*)oh)[e] = *(uint4*)hv;
        ((uint4*)ol)[e] = *(uint4*)lv;
      }
    }
  } else {
    int e = (bid - 1024) * 256 + threadIdx.x;
    if (e < 9 * 128 * 2048) {
      int tap = e / (128 * 2048);
      int rem = e - tap * (128 * 2048);
      int oc = rem >> 11, ic = rem & 2047;
      float v = w[((size_t)oc * 2048 + ic) * 9 + tap];
      unsigned short h = f2bf(v);
      wTh[e] = h;
      wTl[e] = f2bf(v - bf2f(h));
    }
  }
}

// ---------------- conv1 MFMA: implicit GEMM, split-bf16, pitched-plane LDS ----------------
// grid 256 = kc(16, fast dim -> B slices XCD-L2-local) x b(16).
// Block: M=224(pad of 196) x N=128 (full oc), 4 waves (wm2 x wn2);
// wave tile M=112 x N=64 (mf7 x nf4) -> flops/LDS-byte 12.4 -> 20.4 vs old nf2.
// LDS plane pitches padded +16B (A: 2064 ush = 4128B, B: 1040 ush = 2080B) = 8-bank
// shift per ic-plane -> all b128 reads AND staging writes conflict-free
// (was 8.87M conflict-cycles/dispatch = ~27% of kernel cycles).
__global__ __launch_bounds__(256, 1)
void conv1_mfma(const unsigned short* __restrict__ aTh, const unsigned short* __restrict__ aTl,
                const unsigned short* __restrict__ wTh, const unsigned short* __restrict__ wTl,
                float* __restrict__ p1) {
  const int bid = blockIdx.x;
  const int kc = bid & 15;
  const int b  = bid >> 4;
  const int tid = threadIdx.x;
  const int wid = tid >> 6, lane = tid & 63;
  const int wm = wid & 1, wn = wid >> 1;
  const int q = lane >> 4, ln = lane & 15;

  __shared__ unsigned short sAh[4 * 2064];   // [icq4][pospad256][8], pitch 2064
  __shared__ unsigned short sAl[4 * 2064];
  __shared__ unsigned short sBh[4 * 1040];   // [icq4][oc128][8], pitch 1040
  __shared__ unsigned short sBl[4 * 1040];

  // zero A once: padded-grid borders stay zero (stages overwrite interior only)
  for (int e = tid; e < 4128; e += 256) {
    ((unsigned int*)sAh)[e] = 0u;
    ((unsigned int*)sAl)[e] = 0u;
  }

  int abase[7];
#pragma unroll
  for (int mf = 0; mf < 7; mf++) {
    int row = wm * 112 + mf * 16 + ln;
    int y = row / 14, x = row - y * 14;
    abase[mf] = ((row < 196) ? (y * 16 + x) : 0) * 8;
  }
  const int qoff = q * 2064;

  f32x4 acc[7][4];
#pragma unroll
  for (int mf = 0; mf < 7; mf++)
#pragma unroll
    for (int nf = 0; nf < 4; nf++) acc[mf][nf] = (f32x4){0.f, 0.f, 0.f, 0.f};

  // B staging map: thread -> (oc = tid>>2 and tid>>2 + 64, icq = tid&3)
  const int boc = tid >> 2, bicq = tid & 3;
  const size_t bocbase0 = (size_t)boc << 11;
  const size_t bocbase1 = (size_t)(boc + 64) << 11;

  uint4 pvh0, pvl0, pvh1, pvl1;
  {
    const size_t g = (size_t)kc * 128 + bicq * 8;   // tap=0, ks=0
    pvh0 = *(const uint4*)(wTh + g + bocbase0);
    pvl0 = *(const uint4*)(wTl + g + bocbase0);
    pvh1 = *(const uint4*)(wTh + g + bocbase1);
    pvl1 = *(const uint4*)(wTl + g + bocbase1);
  }

  for (int it = 0; it < 36; it++) {
    const int ks = it / 9, tap = it - ks * 9;
    __syncthreads();
    *(uint4*)(sBh + bicq * 1040 + boc * 8) = pvh0;
    *(uint4*)(sBl + bicq * 1040 + boc * 8) = pvl0;
    *(uint4*)(sBh + bicq * 1040 + boc * 8 + 512) = pvh1;
    *(uint4*)(sBl + bicq * 1040 + boc * 8 + 512) = pvl1;
    if (tap == 0) {
      const uint4* gh = (const uint4*)(aTh + ((size_t)(b * 64 + kc * 4 + ks) * 196) * 32);
      const uint4* gl = (const uint4*)(aTl + ((size_t)(b * 64 + kc * 4 + ks) * 196) * 32);
#pragma unroll
      for (int r = 0; r < 4; r++) {
        int e = tid + 256 * r;               // e = pos*4 + icq
        if (e < 784) {
          int pos = e >> 2, part = e & 3;
          int py = pos / 14, px = pos - py * 14;
          int dst = part * 2064 + ((py + 1) * 16 + px + 1) * 8;
          *(uint4*)(sAh + dst) = gh[e];
          *(uint4*)(sAl + dst) = gl[e];
        }
      }
    }
    __syncthreads();
    // prefetch next tap's B AFTER the barrier: its vmcnt drain lands at the
    // NEXT barrier, hidden under this iteration's MFMA phase (1 block/CU now).
    {
      const int nit = (it < 35) ? it + 1 : 35;
      const int ks2 = nit / 9, tap2 = nit - ks2 * 9;
      const size_t g = (size_t)tap2 * (128 * 2048) + kc * 128 + ks2 * 32 + bicq * 8;
      pvh0 = *(const uint4*)(wTh + g + bocbase0);
      pvl0 = *(const uint4*)(wTl + g + bocbase0);
      pvh1 = *(const uint4*)(wTh + g + bocbase1);
      pvl1 = *(const uint4*)(wTl + g + bocbase1);
    }

    const int t8 = ((tap / 3) * 16 + (tap % 3)) * 8;
    bf16x8 bh[4], bl[4];
#pragma unroll
    for (int nf = 0; nf < 4; nf++) {
      const int bb = q * 1040 + (wn * 64 + nf * 16 + ln) * 8;
      bh[nf] = *(const bf16x8*)(sBh + bb);
      bl[nf] = *(const bf16x8*)(sBl + bb);
    }
#pragma unroll
    for (int mf = 0; mf < 7; mf++) {
      bf16x8 ah = *(const bf16x8*)(sAh + qoff + abase[mf] + t8);
      bf16x8 al = *(const bf16x8*)(sAl + qoff + abase[mf] + t8);
#pragma unroll
      for (int nf = 0; nf < 4; nf++) {
        acc[mf][nf] = __builtin_amdgcn_mfma_f32_16x16x32_bf16(ah, bh[nf], acc[mf][nf], 0, 0, 0);
        acc[mf][nf] = __builtin_amdgcn_mfma_f32_16x16x32_bf16(al, bh[nf], acc[mf][nf], 0, 0, 0);
        acc[mf][nf] = __builtin_amdgcn_mfma_f32_16x16x32_bf16(ah, bl[nf], acc[mf][nf], 0, 0, 0);
      }
    }
  }

  // p1[kc][b][pos196][oc128], coalesced 64B segments
  float* pk = p1 + ((size_t)kc * NB + b) * 196 * 128;
#pragma unroll
  for (int mf = 0; mf < 7; mf++) {
    const int row0 = wm * 112 + mf * 16 + q * 4;
#pragma unroll
    for (int nf = 0; nf < 4; nf++) {
      const int oc = wn * 64 + nf * 16 + ln;
#pragma unroll
      for (int r = 0; r < 4; r++) {
        const int row = row0 + r;
        if (row < 196) pk[(size_t)row * 128 + oc] = acc[mf][nf][r];
      }
    }
  }
}

// finish: sum 16 kc slabs + bias + relu; LDS transpose -> coalesced d1[b][oc][pos] writes
__global__ __launch_bounds__(256)
void conv1_finish_p(const float* __restrict__ p1, const float* __restrict__ bias,
                    float* __restrict__ d1) {
  __shared__ float s[28 * 132];
  const int bid = blockIdx.x;       // 112 = 16 b x 7 pos-tiles(28)
  const int pt = bid % 7, b = bid / 7;
  const int tid = threadIdx.x;
#pragma unroll
  for (int r = 0; r < 4; r++) {
    int u = tid + 256 * r;
    if (u < 896) {
      int pos = u >> 5, oc4 = u & 31;
      const float* base = p1 + ((size_t)(b * 196 + pt * 28 + pos)) * 128 + oc4 * 4;
      float4 sum = ((const float4*)bias)[oc4];
#pragma unroll
      for (int k = 0; k < 16; k++) {
        float4 v = *(const float4*)(base + (size_t)k * NBP);
        sum.x += v.x; sum.y += v.y; sum.z += v.z; sum.w += v.w;
      }
      sum.x = fmaxf(sum.x, 0.f); sum.y = fmaxf(sum.y, 0.f);
      sum.z = fmaxf(sum.z, 0.f); sum.w = fmaxf(sum.w, 0.f);
      *(float4*)(s + pos * 132 + oc4 * 4) = sum;
    }
  }
  __syncthreads();
#pragma unroll
  for (int r = 0; r < 4; r++) {
    int u = tid + 256 * r;
    if (u < 896) {
      int oc = u / 7, f = u - oc * 7;
      float4 v;
      v.x = s[(f * 4 + 0) * 132 + oc];
      v.y = s[(f * 4 + 1) * 132 + oc];
      v.z = s[(f * 4 + 2) * 132 + oc];
      v.w = s[(f * 4 + 3) * 132 + oc];
      *(float4*)(d1 + ((size_t)b * 128 + oc) * 196 + pt * 28 + f * 4) = v;
    }
  }
}

// ---------------- conv2: d1 [16,128,14,14] -> partials, stride2 pad1 ----------------
__global__ void conv2_part(const float* __restrict__ d1, const float* __restrict__ w,
                           float* __restrict__ p2) {
  const int bid = blockIdx.x;
  const int kc = bid & 3, oct = (bid >> 2) & 3, b = bid >> 4;
  const int ic0 = kc * 32, oc0 = oct * 32;
  const int tid = threadIdx.x;
  const int ocl = tid >> 3, rw = tid & 7;

  __shared__ float s_in[32 * 320];
  __shared__ float s_w[32 * 324];

#pragma unroll
  for (int r = 0; r < 32; r++) {
    const int e = tid + 256 * r;
    const int ch = e >> 8, idx = e & 255;
    const int tr = idx >> 4, tc = idx & 15;
    const int iy = tr - 1, ix = tc - 1;
    float v = 0.f;
    if ((unsigned)iy < 14u && (unsigned)ix < 14u)
      v = d1[((size_t)b * 128 + ic0 + ch) * 196 + iy * 14 + ix];
    s_in[ch * 320 + tr * 20 + tc] = v;
  }
#pragma unroll
  for (int r = 0; r < 36; r++) {
    const int e = tid + 256 * r;
    const int oc = e / 288, rem = e - oc * 288;
    const int ch = rem / 9, tap = rem - ch * 9;
    s_w[ch * 324 + tap * 36 + oc] =
        w[(size_t)(oc0 + oc) * 1152 + (size_t)ic0 * 9 + rem];
  }
  __syncthreads();

  if (rw < 7) {
    float acc[7] = {};
    for (int ic = 0; ic < 32; ic++) {
      const float* wrow = s_w + ic * 324 + ocl;
      const float* irow = s_in + ic * 320;
#pragma unroll
      for (int ky = 0; ky < 3; ky++) {
        const float* r = irow + (2 * rw + ky) * 20;
        const float4 f0 = *(const float4*)(r);
        const float4 f1 = *(const float4*)(r + 4);
        const float4 f2 = *(const float4*)(r + 8);
        const float4 f3 = *(const float4*)(r + 12);
        const float ev[8] = {f0.x, f0.z, f1.x, f1.z, f2.x, f2.z, f3.x, f3.z};
        const float od[7] = {f0.y, f0.w, f1.y, f1.w, f2.y, f2.w, f3.y};
        const float w0 = wrow[(ky * 3 + 0) * 36];
        const float w1 = wrow[(ky * 3 + 1) * 36];
        const float w2 = wrow[(ky * 3 + 2) * 36];
#pragma unroll
        for (int x = 0; x < 7; x++)
          acc[x] = fmaf(w0, ev[x], fmaf(w1, od[x], fmaf(w2, ev[x + 1], acc[x])));
      }
    }
    float* po = p2 + (((size_t)kc * NB + b) * 128 + oc0 + ocl) * 49 + rw * 7;
#pragma unroll
    for (int x = 0; x < 7; x++) po[x] = acc[x];
  }
}

__global__ void conv2_finish(const float* __restrict__ p2, const float* __restrict__ bias,
                             float* __restrict__ d2) {
  const int i = blockIdx.x * 256 + threadIdx.x;
  if (i >= NB * 128 * 49) return;
  const int oc = (i / 49) & 127;
  float s = bias[oc];
#pragma unroll
  for (int k = 0; k < 4; k++) s += p2[(size_t)k * (NB * 128 * 49) + i];
  d2[i] = fmaxf(s, 0.f);
}

// ---------------- conv3: d2 [16,128,7,7] -> partials, stride2 pad1 ----------------
__global__ void conv3_part(const float* __restrict__ d2, const float* __restrict__ w,
                           float* __restrict__ p3) {
  const int bid = blockIdx.x;
  const int kc = bid & 1, oct = (bid >> 1) & 7, b = bid >> 4;
  const int ic0 = kc * 64, oc0 = oct * 16;
  const int tid = threadIdx.x;
  const int oc = tid >> 4, p = tid & 15;
  const int y = p >> 2, x = p & 3;

  __shared__ float s_in[64 * 108];
  __shared__ float s_w[64 * 144];

#pragma unroll
  for (int r = 0; r < 21; r++) {
    const int e = tid + 256 * r;
    if (e < 64 * 81) {
      const int ch = e / 81, idx = e - ch * 81;
      const int tr = idx / 9, tc = idx - tr * 9;
      const int iy = tr - 1, ix = tc - 1;
      float v = 0.f;
      if ((unsigned)iy < 7u && (unsigned)ix < 7u)
        v = d2[((size_t)b * 128 + ic0 + ch) * 49 + iy * 7 + ix];
      s_in[ch * 108 + tr * 12 + tc] = v;
    }
  }
#pragma unroll
  for (int r = 0; r < 36; r++) {
    const int e = tid + 256 * r;
    const int o = e / 576, rem = e - o * 576;
    const int ch = rem / 9, tap = rem - ch * 9;
    s_w[ch * 144 + tap * 16 + o] =
        w[(size_t)(oc0 + o) * 1152 + (size_t)ic0 * 9 + rem];
  }
  __syncthreads();

  float acc = 0.f;
  for (int ic = 0; ic < 64; ic++) {
    const float* wrow = s_w + ic * 144 + oc;
    const float* irow = s_in + ic * 108 + 2 * y * 12 + 2 * x;
#pragma unroll
    for (int ky = 0; ky < 3; ky++)
#pragma unroll
      for (int kx = 0; kx < 3; kx++)
        acc = fmaf(wrow[(ky * 3 + kx) * 16], irow[ky * 12 + kx], acc);
  }
  p3[(((size_t)kc * NB + b) * 128 + oc0 + oc) * 16 + p] = acc;
}

// ---------------- fused tidy(1x1 convs) + NMS; d3 folded in from p3 ----------------
__global__ __launch_bounds__(256, 1)
void score_nms(const float* __restrict__ d1, const float* __restrict__ d2,
               const float* __restrict__ p3, const float* __restrict__ bd3,
               const float* __restrict__ w1, const float* __restrict__ b1,
               const float* __restrict__ w2, const float* __restrict__ b2,
               const float* __restrict__ w3, const float* __restrict__ b3,
               const int* __restrict__ anchors, float* __restrict__ score,
               float* __restrict__ out_idx, float* __restrict__ out_prob,
               float* __restrict__ sel) {
  __shared__ float s_in[32 * 200];     // t1 chunks; reused linearly for d2 (6272) / d3 (2048)
  __shared__ float s_w[21 * 128];      // w1(0..5), w2(6..11), w3(12..20)
  __shared__ float s_b[21];
  __shared__ float s_sc[NA];
  __shared__ float s_bx[NA * 4];
  __shared__ float r_s[256];
  __shared__ int r_i[256];
  const int b = blockIdx.x, tid = threadIdx.x;

  for (int i = tid; i < 768; i += 256) s_w[i] = w1[i];
  for (int i = tid; i < 768; i += 256) s_w[768 + i] = w2[i];
  for (int i = tid; i < 1152; i += 256) s_w[1536 + i] = w3[i];
  if (tid < 21) s_b[tid] = (tid < 6) ? b1[tid] : (tid < 12) ? b2[tid - 6] : b3[tid - 12];
  for (int i = tid; i < NA; i += 256) {
    s_bx[i * 4 + 0] = (float)anchors[i * 4 + 0];
    s_bx[i * 4 + 1] = (float)anchors[i * 4 + 1];
    s_bx[i * 4 + 2] = (float)anchors[i * 4 + 2];
    s_bx[i * 4 + 3] = (float)anchors[i * 4 + 3];
  }

  // ---- t1: 6 oc x 196 pos = 1176 scores, d1 staged in 4 chunks of 32 ic ----
  float acc[5] = {0.f, 0.f, 0.f, 0.f, 0.f};
  for (int chunk = 0; chunk < 4; chunk++) {
    __syncthreads();
    const float* src = d1 + ((size_t)b * 128 + chunk * 32) * 196;
#pragma unroll
    for (int r = 0; r < 7; r++) {
      int e = tid + 256 * r;
      if (e < 1568) {
        int ic = e / 49, f = e - ic * 49;
        *(float4*)(s_in + ic * 200 + f * 4) = ((const float4*)(src + (size_t)ic * 196))[f];
      }
    }
    __syncthreads();
#pragma unroll
    for (int k = 0; k < 5; k++) {
      int j = tid + 256 * k;
      if (j < 1176) {
        int oc = j / 196, p = j - oc * 196;
        const float* wr = s_w + oc * 128 + chunk * 32;
        float s = acc[k];
#pragma unroll
        for (int ic = 0; ic < 32; ic++) s = fmaf(wr[ic], s_in[ic * 200 + p], s);
        acc[k] = s;
      }
    }
  }
#pragma unroll
  for (int k = 0; k < 5; k++) {
    int j = tid + 256 * k;
    if (j < 1176) {
      int oc = j / 196;
      float s = acc[k] + s_b[oc];
      s_sc[j] = s;
      score[b * NA + j] = s;
    }
  }

  // ---- t2: 6 oc x 49 = 294 scores, d2[b] staged fully (linear) ----
  __syncthreads();
  {
    const float* src = d2 + (size_t)b * 6272;
#pragma unroll
    for (int r = 0; r < 7; r++) {
      int e = tid + 256 * r;
      if (e < 1568) *(float4*)(s_in + e * 4) = ((const float4*)src)[e];
    }
  }
  __syncthreads();
#pragma unroll
  for (int k = 0; k < 2; k++) {
    int jj = tid + 256 * k;
    if (jj < 294) {
      int oc = jj / 49, p = jj - oc * 49;
      const float* wr = s_w + 768 + oc * 128;
      float s = s_b[6 + oc];
#pragma unroll 8
      for (int ic = 0; ic < 128; ic++) s = fmaf(wr[ic], s_in[ic * 49 + p], s);
      s_sc[1176 + jj] = s;
      score[b * NA + 1176 + jj] = s;
    }
  }

  // ---- t3: 9 oc x 16 = 144 scores; d3 = relu(p3[0]+p3[1]+bd3) computed inline ----
  __syncthreads();
  {
    const float4* s0 = (const float4*)(p3 + (size_t)b * 2048);
    const float4* s1 = (const float4*)(p3 + 32768 + (size_t)b * 2048);
#pragma unroll
    for (int r = 0; r < 2; r++) {
      int e = tid + 256 * r;
      if (e < 512) {
        float4 a = s0[e], c = s1[e];
        float bb = bd3[e >> 2];
        float4 v;
        v.x = fmaxf(a.x + c.x + bb, 0.f);
        v.y = fmaxf(a.y + c.y + bb, 0.f);
        v.z = fmaxf(a.z + c.z + bb, 0.f);
        v.w = fmaxf(a.w + c.w + bb, 0.f);
        *(float4*)(s_in + e * 4) = v;
      }
    }
  }
  __syncthreads();
  if (tid < 144) {
    int oc = tid >> 4, p = tid & 15;
    const float* wr = s_w + 1536 + oc * 128;
    float s = s_b[12 + oc];
#pragma unroll 8
    for (int ic = 0; ic < 128; ic++) s = fmaf(wr[ic], s_in[ic * 16 + p], s);
    s_sc[1470 + tid] = s;
    score[b * NA + 1470 + tid] = s;
  }
  __syncthreads();

  // ---- NMS: TOPN=4, IoU>0.25 suppress ----
  for (int t = 0; t < 4; t++) {
    float bs = -__builtin_inff();
    int bi = NA;
    for (int i = tid; i < NA; i += 256) {
      float s = s_sc[i];
      if (s > bs || (s == bs && i < bi)) { bs = s; bi = i; }
    }
    r_s[tid] = bs; r_i[tid] = bi;
    __syncthreads();
    for (int off = 128; off > 0; off >>= 1) {
      if (tid < off) {
        float s2 = r_s[tid + off]; int i2 = r_i[tid + off];
        if (s2 > r_s[tid] || (s2 == r_s[tid] && i2 < r_i[tid])) { r_s[tid] = s2; r_i[tid] = i2; }
      }
      __syncthreads();
    }
    const int idx = r_i[0];
    const float by0 = s_bx[idx * 4 + 0], bx0 = s_bx[idx * 4 + 1];
    const float by1 = s_bx[idx * 4 + 2], bx1 = s_bx[idx * 4 + 3];
    if (tid == 0) {
      out_idx[b * 4 + t] = (float)idx;
      out_prob[b * 4 + t] = s_sc[idx];
      sel[(b * 4 + t) * 4 + 0] = by0;
      sel[(b * 4 + t) * 4 + 1] = bx0;
      sel[(b * 4 + t) * 4 + 2] = by1;
      sel[(b * 4 + t) * 4 + 3] = bx1;
    }
    __syncthreads();
    const float a = (by1 - by0) * (bx1 - bx0);
    for (int i = tid; i < NA; i += 256) {
      float cy0 = s_bx[i * 4 + 0], cx0 = s_bx[i * 4 + 1];
      float cy1 = s_bx[i * 4 + 2], cx1 = s_bx[i * 4 + 3];
      float yy0 = fmaxf(by0, cy0), xx0 = fmaxf(bx0, cx0);
      float yy1 = fminf(by1, cy1), xx1 = fminf(bx1, cx1);
      float inter = fmaxf(yy1 - yy0, 0.f) * fmaxf(xx1 - xx0, 0.f);
      float ar = (cy1 - cy0) * (cx1 - cx0);
      float iou = inter / (a + ar - inter);
      if (iou > 0.25f) s_sc[i] = -__builtin_inff();
    }
    __syncthreads();
  }
}

// ---------------- crop+bilinear resize to [16,4,3,224,224], 4 px/thread ----------------
__global__ void crop_kernel(const float* __restrict__ x, const float* __restrict__ sel,
                            float* __restrict__ out) {
  int i4 = blockIdx.x * 256 + threadIdx.x;
  const int total4 = NB * 4 * 3 * 224 * 56;
  if (i4 >= total4) return;
  int px0 = (i4 % 56) * 4;
  int t = i4 / 56;
  int py = t % 224; t /= 224;
  int ch = t % 3;  t /= 3;
  int n  = t % 4;
  int b  = t / 4;

  const float* bx = sel + (b * 4 + n) * 4;
  const float y0 = bx[0], x0 = bx[1], y1 = bx[2], x1 = bx[3];

  float ty = (float)py / 223.0f;
  float cy = y0 + (y1 - 1.0f - y0) * ty;
  float cyf = floorf(cy);
  int ylo = (int)cyf; ylo = ylo < 0 ? 0 : (ylo > 895 ? 895 : ylo);
  int yhi = ylo + 1 > 895 ? 895 : ylo + 1;
  float wy = cy - cyf;

  const float* img = x + ((size_t)b * 3 + ch) * 448 * 448;
  auto g = [&](int yy, int xx) -> float {
    yy -= 224; xx -= 224;
    if ((unsigned)yy < 448u && (unsigned)xx < 448u)
      return img[(size_t)yy * 448 + xx];
    return 0.f;
  };

  float4 res;
  float* rp = &res.x;
#pragma unroll
  for (int k = 0; k < 4; k++) {
    float tx = (float)(px0 + k) / 223.0f;
    float cx = x0 + (x1 - 1.0f - x0) * tx;
    float cxf = floorf(cx);
    int xlo = (int)cxf; xlo = xlo < 0 ? 0 : (xlo > 895 ? 895 : xlo);
    int xhi = xlo + 1 > 895 ? 895 : xlo + 1;
    float wx = cx - cxf;
    float v00 = g(ylo, xlo), v01 = g(ylo, xhi);
    float v10 = g(yhi, xlo), v11 = g(yhi, xhi);
    rp[k] = (1.f - wy) * ((1.f - wx) * v00 + wx * v01) +
            wy * ((1.f - wx) * v10 + wx * v11);
  }
  *(float4*)(out + (size_t)i4 * 4) = res;
}

extern "C" void kernel_launch(void* const* d_in, const int* in_sizes, int n_in,
                              void* d_out, int out_size, void* d_ws, size_t ws_size,
                              hipStream_t stream) {
  const float* x    = (const float*)d_in[0];
  const float* rpn  = (const float*)d_in[1];
  const int*   anc  = (const int*)d_in[2];
  const float* w_d1 = (const float*)d_in[3];
  const float* b_d1 = (const float*)d_in[4];
  const float* w_d2 = (const float*)d_in[5];
  const float* b_d2 = (const float*)d_in[6];
  const float* w_d3 = (const float*)d_in[7];
  const float* b_d3 = (const float*)d_in[8];
  const float* w_t1 = (const float*)d_in[9];
  const float* b_t1 = (const float*)d_in[10];
  const float* w_t2 = (const float*)d_in[11];
  const float* b_t2 = (const float*)d_in[12];
  const float* w_t3 = (const float*)d_in[13];
  const float* b_t3 = (const float*)d_in[14];

  float* out = (float*)d_out;
  float* ws = (float*)d_ws;

  float* d1  = ws;                        // 401408
  float* d2  = d1 + 401408;               // 100352
  float* d3  = d2 + 100352;               // 32768 (unused slot, kept for layout stability)
  float* sel = d3 + 32768;                // 256
  float* p2  = sel + 256;                 // 401408
  float* p3  = p2 + 401408;               // 65536
  unsigned short* wTh = (unsigned short*)(p3 + 65536);   // 2,359,296 ush
  unsigned short* wTl = wTh + 2359296;                   // 2,359,296 ush
  unsigned short* aTh = wTl + 2359296;                   // 6,422,528 ush
  unsigned short* aTl = aTh + 6422528;                   // 6,422,528 ush
  // total ws need: 39,134,208 B (identical to round 5/6 verified layout)

  float* score    = out;                  // 25824
  float* out_idx  = out + 25824;          // 64
  float* out_prob = out + 25888;          // 64
  float* parts    = out + 25952;          // 9,633,792 (final crop output)
  float* p1       = parts;                // 6,422,528 floats scratch; crop overwrites after

  prep<<<dim3(10240), dim3(256), 0, stream>>>(w_d1, rpn, wTh, wTl, aTh, aTl);
  conv1_mfma<<<dim3(256), dim3(256), 0, stream>>>(aTh, aTl, wTh, wTl, p1);
  conv1_finish_p<<<dim3(112), dim3(256), 0, stream>>>(p1, b_d1, d1);
  conv2_part<<<dim3(256), dim3(256), 0, stream>>>(d1, w_d2, p2);
  conv2_finish<<<dim3(392), dim3(256), 0, stream>>>(p2, b_d2, d2);
  conv3_part<<<dim3(256), dim3(256), 0, stream>>>(d2, w_d3, p3);
  score_nms<<<dim3(16), dim3(256), 0, stream>>>(d1, d2, p3, b_d3, w_t1, b_t1, w_t2, b_t2,
                                                w_t3, b_t3, anc, score, out_idx, out_prob, sel);
  crop_kernel<<<dim3(9408), dim3(256), 0, stream>>>(x, sel, parts);
}

// Round 2
// 274.612 us; speedup vs baseline: 1.0413x; 1.0413x over previous
//
#include <hip/hip_runtime.h>
#include <hip/hip_bf16.h>

#define NB 16
#define NA 1614
#define NBP (NB * 196 * 128)   // p1 slab stride = 401408

typedef __bf16 bf16x8 __attribute__((ext_vector_type(8)));
typedef float f32x4 __attribute__((ext_vector_type(4)));

__device__ __forceinline__ unsigned short f2bf(float v) {
  unsigned u = __float_as_uint(v);
  unsigned r = (u + 0x7FFFu + ((u >> 16) & 1u)) >> 16;
  return (unsigned short)r;
}
__device__ __forceinline__ float bf2f(unsigned short s) {
  return __uint_as_float(((unsigned)s) << 16);
}

// ---------------- prep (fused): blocks [0,1024) transpose+split rpn -> aT; rest -> wT ------
// aT layout: [chunk = b*64 + ic32grp][pos196][ic32] hi/lo, written fully coalesced (pos-major).
// wT layout (NEW): [kc16][tap9][ks4][oc128][icq4][8] hi/lo -> conv1 B-fragment reads are
// fully coalesced 1KB/wave global loads (no B LDS staging needed).
__global__ __launch_bounds__(256)
void prep(const float* __restrict__ w, const float* __restrict__ in,
          unsigned short* __restrict__ wTh, unsigned short* __restrict__ wTl,
          unsigned short* __restrict__ aTh, unsigned short* __restrict__ aTl) {
  __shared__ float s[32 * 201];
  const int bid = blockIdx.x;
  if (bid < 1024) {
    const int chunk = bid & 63, b = bid >> 6;
    const float* src = in + ((size_t)b * 2048 + chunk * 32) * 196;
#pragma unroll
    for (int r = 0; r < 7; r++) {
      int e = threadIdx.x + 256 * r;
      if (e < 1568) {
        int ic = e / 49, f = e - ic * 49;
        float4 v = ((const float4*)(src + (size_t)ic * 196))[f];
        float* d = s + ic * 201 + f * 4;
        d[0] = v.x; d[1] = v.y; d[2] = v.z; d[3] = v.w;
      }
    }
    __syncthreads();
    unsigned short* oh = aTh + (size_t)bid * (196 * 32);
    unsigned short* ol = aTl + (size_t)bid * (196 * 32);
#pragma unroll
    for (int r = 0; r < 4; r++) {
      int e = threadIdx.x + 256 * r;   // uint4 units; e = pos*4 + part -> contiguous writes
      if (e < 784) {
        int pos = e >> 2, part = e & 3;
        unsigned short hv[8], lv[8];
#pragma unroll
        for (int j = 0; j < 8; j++) {
          float v = s[(part * 8 + j) * 201 + pos];
          unsigned short h = f2bf(v);
          hv[j] = h;
          lv[j] = f2bf(v - bf2f(h));
        }
        ((uint4*)oh)[e] = *(uint4*)hv;
        ((uint4*)ol)[e] = *(uint4*)lv;
      }
    }
  } else {
    int e = (bid - 1024) * 256 + threadIdx.x;
    if (e < 9 * 128 * 2048) {
      int tap = e / (128 * 2048);
      int rem = e - tap * (128 * 2048);
      int oc = rem >> 11, ic = rem & 2047;
      // decompose ic = kc*128 + ks*32 + icq*8 + j
      int kcp = ic >> 7, ks = (ic >> 5) & 3, icq = (ic >> 3) & 3, j = ic & 7;
      size_t g2 = ((size_t)(kcp * 36 + tap * 4 + ks) << 12) + oc * 32 + icq * 8 + j;
      float v = w[((size_t)oc * 2048 + ic) * 9 + tap];
      unsigned short h = f2bf(v);
      wTh[g2] = h;
      wTl[g2] = f2bf(v - bf2f(h));
    }
  }
}

// ---------------- conv1 MFMA: implicit GEMM, split-bf16 ----------------
// grid 256 = kc(16, fast dim -> B slices XCD-L2-local) x b(16), 1 block/CU.
// Block M=224(pad of 196) x N=128, 4 waves (wm2 x wn2); wave tile M112 x N64 (mf7 x nf4).
// Structure for 1-wave/SIMD latency tolerance:
//  - B fragments loaded DIRECTLY from global (L2-resident, coalesced via new wT layout),
//    register double-buffered one iter ahead -> no B LDS, no per-iter barrier.
//  - A tile double-buffered in LDS; next-ks staged spread over taps 2..6 (load tap t,
//    ds_write tap t+1) -> only 1 barrier per ks boundary (4 total).
//  - MFMA pass-outer order: 28 independent MFMAs between dependent accumulator reuses.
//    Per-acc call order per iter unchanged (ah*bh, al*bh, ah*bl) -> bit-identical results.
// LDS A plane: [icq4][row16 x col16 x 8], row pitch 136 ush, plane pitch 2192 ush
// (4/8-bank shifts -> reduced read conflicts).
#define APL 2192          // ush per icq plane
#define ABUF (4 * APL)    // ush per A buffer (8768)

#define LOADB(H, L, T, K)                                                     \
  {                                                                           \
    const size_t o_ = ((size_t)(kc * 36 + (T) * 4 + (K)) << 12) + bln;        \
    const unsigned short* ph_ = wTh + o_;                                     \
    const unsigned short* pq_ = wTl + o_;                                     \
    H[0] = *(const bf16x8*)(ph_);                                             \
    H[1] = *(const bf16x8*)(ph_ + 512);                                       \
    H[2] = *(const bf16x8*)(ph_ + 1024);                                      \
    H[3] = *(const bf16x8*)(ph_ + 1536);                                      \
    L[0] = *(const bf16x8*)(pq_);                                             \
    L[1] = *(const bf16x8*)(pq_ + 512);                                       \
    L[2] = *(const bf16x8*)(pq_ + 1024);                                      \
    L[3] = *(const bf16x8*)(pq_ + 1536);                                      \
  }

#define STEP(IT, BUH, BUL, BNH, BNL)                                          \
  {                                                                           \
    const int it_ = (IT);                                                     \
    const int ks_ = it_ / 9, tap_ = it_ - ks_ * 9;                            \
    { /* prefetch next iter's B into the alternate register set */            \
      const int ni_ = (it_ < 35) ? it_ + 1 : 35;                              \
      const int nk_ = ni_ / 9, nt_ = ni_ - nk_ * 9;                           \
      LOADB(BNH, BNL, nt_, nk_);                                              \
    }                                                                         \
    if (ks_ < 3) { /* spread next-ks A staging: load tap 2..5, write 3..6 */  \
      const uint4* gh_ = (const uint4*)(aTh + ((size_t)(b * 64 + kc * 4 + ks_ + 1) * 196) * 32); \
      const uint4* gl_ = (const uint4*)(aTl + ((size_t)(b * 64 + kc * 4 + ks_ + 1) * 196) * 32); \
      if (tap_ >= 3 && tap_ <= 6) {                                           \
        int e_ = tid + 256 * (tap_ - 3);                                      \
        if (e_ < 784) {                                                       \
          int pos_ = e_ >> 2, part_ = e_ & 3;                                 \
          int py_ = pos_ / 14, px_ = pos_ - py_ * 14;                         \
          int d_ = (((ks_ + 1) & 1) ? ABUF : 0) + part_ * APL + (py_ + 1) * 136 + (px_ + 1) * 8; \
          *(uint4*)(sAh + d_) = sgh;                                          \
          *(uint4*)(sAl + d_) = sgl;                                          \
        }                                                                     \
      }                                                                       \
      if (tap_ >= 2 && tap_ <= 5) {                                           \
        int e_ = tid + 256 * (tap_ - 2);                                      \
        if (e_ < 784) { sgh = gh_[e_]; sgl = gl_[e_]; }                       \
      }                                                                       \
    }                                                                         \
    const int t8_ = (tap_ / 3) * 136 + (tap_ - (tap_ / 3) * 3) * 8;           \
    const unsigned short* pah_ = sAh + (ks_ & 1) * ABUF + qoff + t8_;         \
    const unsigned short* pal_ = sAl + (ks_ & 1) * ABUF + qoff + t8_;         \
    bf16x8 afh[7], afl[7];                                                    \
    _Pragma("unroll") for (int mf = 0; mf < 7; mf++) {                        \
      afh[mf] = *(const bf16x8*)(pah_ + abase[mf]);                           \
      afl[mf] = *(const bf16x8*)(pal_ + abase[mf]);                           \
    }                                                                         \
    _Pragma("unroll") for (int mf = 0; mf < 7; mf++)                          \
      _Pragma("unroll") for (int nf = 0; nf < 4; nf++)                        \
        acc[mf][nf] = __builtin_amdgcn_mfma_f32_16x16x32_bf16(afh[mf], BUH[nf], acc[mf][nf], 0, 0, 0); \
    _Pragma("unroll") for (int mf = 0; mf < 7; mf++)                          \
      _Pragma("unroll") for (int nf = 0; nf < 4; nf++)                        \
        acc[mf][nf] = __builtin_amdgcn_mfma_f32_16x16x32_bf16(afl[mf], BUH[nf], acc[mf][nf], 0, 0, 0); \
    _Pragma("unroll") for (int mf = 0; mf < 7; mf++)                          \
      _Pragma("unroll") for (int nf = 0; nf < 4; nf++)                        \
        acc[mf][nf] = __builtin_amdgcn_mfma_f32_16x16x32_bf16(afh[mf], BUL[nf], acc[mf][nf], 0, 0, 0); \
    if (tap_ == 8) __syncthreads();                                           \
  }

__global__ __launch_bounds__(256, 1)
void conv1_mfma(const unsigned short* __restrict__ aTh, const unsigned short* __restrict__ aTl,
                const unsigned short* __restrict__ wTh, const unsigned short* __restrict__ wTl,
                float* __restrict__ p1) {
  const int bid = blockIdx.x;
  const int kc = bid & 15;
  const int b  = bid >> 4;
  const int tid = threadIdx.x;
  const int wid = tid >> 6, lane = tid & 63;
  const int wm = wid & 1, wn = wid >> 1;
  const int q = lane >> 4, ln = lane & 15;

  __shared__ unsigned short sAh[2 * ABUF];
  __shared__ unsigned short sAl[2 * ABUF];

  // zero both A buffers once: padded borders stay zero (stages overwrite interior only)
  for (int e = tid; e < ABUF; e += 256) {     // ABUF ush pairs = 2*ABUF ush as u32
    ((unsigned int*)sAh)[e] = 0u;
    ((unsigned int*)sAl)[e] = 0u;
  }

  int abase[7];
#pragma unroll
  for (int mf = 0; mf < 7; mf++) {
    int row = wm * 112 + mf * 16 + ln;
    int y = row / 14, x = row - y * 14;
    abase[mf] = (row < 196) ? (y * 136 + x * 8) : 0;
  }
  const int qoff = q * APL;
  const int bln = (wn * 64 + ln) * 32 + q * 8;   // per-lane B offset (oc-major coalesced)

  f32x4 acc[7][4];
#pragma unroll
  for (int mf = 0; mf < 7; mf++)
#pragma unroll
    for (int nf = 0; nf < 4; nf++) acc[mf][nf] = (f32x4){0.f, 0.f, 0.f, 0.f};

  uint4 sgh, sgl;   // in-flight A staging registers (load tap t, LDS-write tap t+1)

  // prologue: stage ks=0 into buffer 0; load iter 0's B
  {
    const uint4* gh = (const uint4*)(aTh + ((size_t)(b * 64 + kc * 4) * 196) * 32);
    const uint4* gl = (const uint4*)(aTl + ((size_t)(b * 64 + kc * 4) * 196) * 32);
#pragma unroll
    for (int r = 0; r < 4; r++) {
      int e = tid + 256 * r;
      if (e < 784) {
        int pos = e >> 2, part = e & 3;
        int py = pos / 14, px = pos - py * 14;
        int d = part * APL + (py + 1) * 136 + (px + 1) * 8;
        *(uint4*)(sAh + d) = gh[e];
        *(uint4*)(sAl + d) = gl[e];
      }
    }
  }
  bf16x8 b0h[4], b0l[4], b1h[4], b1l[4];
  LOADB(b0h, b0l, 0, 0);
  __syncthreads();

  for (int it = 0; it < 36; it += 2) {
    STEP(it,     b0h, b0l, b1h, b1l);
    STEP(it + 1, b1h, b1l, b0h, b0l);
  }

  // p1[kc][b][pos196][oc128], coalesced 64B segments
  float* pk = p1 + ((size_t)kc * NB + b) * 196 * 128;
#pragma unroll
  for (int mf = 0; mf < 7; mf++) {
    const int row0 = wm * 112 + mf * 16 + q * 4;
#pragma unroll
    for (int nf = 0; nf < 4; nf++) {
      const int oc = wn * 64 + nf * 16 + ln;
#pragma unroll
      for (int r = 0; r < 4; r++) {
        const int row = row0 + r;
        if (row < 196) pk[(size_t)row * 128 + oc] = acc[mf][nf][r];
      }
    }
  }
}

// finish: sum 16 kc slabs + bias + relu; LDS transpose -> coalesced d1[b][oc][pos] writes
__global__ __launch_bounds__(256)
void conv1_finish_p(const float* __restrict__ p1, const float* __restrict__ bias,
                    float* __restrict__ d1) {
  __shared__ float s[28 * 132];
  const int bid = blockIdx.x;       // 112 = 16 b x 7 pos-tiles(28)
  const int pt = bid % 7, b = bid / 7;
  const int tid = threadIdx.x;
#pragma unroll
  for (int r = 0; r < 4; r++) {
    int u = tid + 256 * r;
    if (u < 896) {
      int pos = u >> 5, oc4 = u & 31;
      const float* base = p1 + ((size_t)(b * 196 + pt * 28 + pos)) * 128 + oc4 * 4;
      float4 sum = ((const float4*)bias)[oc4];
#pragma unroll
      for (int k = 0; k < 16; k++) {
        float4 v = *(const float4*)(base + (size_t)k * NBP);
        sum.x += v.x; sum.y += v.y; sum.z += v.z; sum.w += v.w;
      }
      sum.x = fmaxf(sum.x, 0.f); sum.y = fmaxf(sum.y, 0.f);
      sum.z = fmaxf(sum.z, 0.f); sum.w = fmaxf(sum.w, 0.f);
      *(float4*)(s + pos * 132 + oc4 * 4) = sum;
    }
  }
  __syncthreads();
#pragma unroll
  for (int r = 0; r < 4; r++) {
    int u = tid + 256 * r;
    if (u < 896) {
      int oc = u / 7, f = u - oc * 7;
      float4 v;
      v.x = s[(f * 4 + 0) * 132 + oc];
      v.y = s[(f * 4 + 1) * 132 + oc];
      v.z = s[(f * 4 + 2) * 132 + oc];
      v.w = s[(f * 4 + 3) * 132 + oc];
      *(float4*)(d1 + ((size_t)b * 128 + oc) * 196 + pt * 28 + f * 4) = v;
    }
  }
}

// ---------------- conv2: d1 [16,128,14,14] -> partials, stride2 pad1 ----------------
__global__ void conv2_part(const float* __restrict__ d1, const float* __restrict__ w,
                           float* __restrict__ p2) {
  const int bid = blockIdx.x;
  const int kc = bid & 3, oct = (bid >> 2) & 3, b = bid >> 4;
  const int ic0 = kc * 32, oc0 = oct * 32;
  const int tid = threadIdx.x;
  const int ocl = tid >> 3, rw = tid & 7;

  __shared__ float s_in[32 * 320];
  __shared__ float s_w[32 * 324];

#pragma unroll
  for (int r = 0; r < 32; r++) {
    const int e = tid + 256 * r;
    const int ch = e >> 8, idx = e & 255;
    const int tr = idx >> 4, tc = idx & 15;
    const int iy = tr - 1, ix = tc - 1;
    float v = 0.f;
    if ((unsigned)iy < 14u && (unsigned)ix < 14u)
      v = d1[((size_t)b * 128 + ic0 + ch) * 196 + iy * 14 + ix];
    s_in[ch * 320 + tr * 20 + tc] = v;
  }
#pragma unroll
  for (int r = 0; r < 36; r++) {
    const int e = tid + 256 * r;
    const int oc = e / 288, rem = e - oc * 288;
    const int ch = rem / 9, tap = rem - ch * 9;
    s_w[ch * 324 + tap * 36 + oc] =
        w[(size_t)(oc0 + oc) * 1152 + (size_t)ic0 * 9 + rem];
  }
  __syncthreads();

  if (rw < 7) {
    float acc[7] = {};
    for (int ic = 0; ic < 32; ic++) {
      const float* wrow = s_w + ic * 324 + ocl;
      const float* irow = s_in + ic * 320;
#pragma unroll
      for (int ky = 0; ky < 3; ky++) {
        const float* r = irow + (2 * rw + ky) * 20;
        const float4 f0 = *(const float4*)(r);
        const float4 f1 = *(const float4*)(r + 4);
        const float4 f2 = *(const float4*)(r + 8);
        const float4 f3 = *(const float4*)(r + 12);
        const float ev[8] = {f0.x, f0.z, f1.x, f1.z, f2.x, f2.z, f3.x, f3.z};
        const float od[7] = {f0.y, f0.w, f1.y, f1.w, f2.y, f2.w, f3.y};
        const float w0 = wrow[(ky * 3 + 0) * 36];
        const float w1 = wrow[(ky * 3 + 1) * 36];
        const float w2 = wrow[(ky * 3 + 2) * 36];
#pragma unroll
        for (int x = 0; x < 7; x++)
          acc[x] = fmaf(w0, ev[x], fmaf(w1, od[x], fmaf(w2, ev[x + 1], acc[x])));
      }
    }
    float* po = p2 + (((size_t)kc * NB + b) * 128 + oc0 + ocl) * 49 + rw * 7;
#pragma unroll
    for (int x = 0; x < 7; x++) po[x] = acc[x];
  }
}

__global__ void conv2_finish(const float* __restrict__ p2, const float* __restrict__ bias,
                             float* __restrict__ d2) {
  const int i = blockIdx.x * 256 + threadIdx.x;
  if (i >= NB * 128 * 49) return;
  const int oc = (i / 49) & 127;
  float s = bias[oc];
#pragma unroll
  for (int k = 0; k < 4; k++) s += p2[(size_t)k * (NB * 128 * 49) + i];
  d2[i] = fmaxf(s, 0.f);
}

// ---------------- conv3: d2 [16,128,7,7] -> partials, stride2 pad1 ----------------
__global__ void conv3_part(const float* __restrict__ d2, const float* __restrict__ w,
                           float* __restrict__ p3) {
  const int bid = blockIdx.x;
  const int kc = bid & 1, oct = (bid >> 1) & 7, b = bid >> 4;
  const int ic0 = kc * 64, oc0 = oct * 16;
  const int tid = threadIdx.x;
  const int oc = tid >> 4, p = tid & 15;
  const int y = p >> 2, x = p & 3;

  __shared__ float s_in[64 * 108];
  __shared__ float s_w[64 * 144];

#pragma unroll
  for (int r = 0; r < 21; r++) {
    const int e = tid + 256 * r;
    if (e < 64 * 81) {
      const int ch = e / 81, idx = e - ch * 81;
      const int tr = idx / 9, tc = idx - tr * 9;
      const int iy = tr - 1, ix = tc - 1;
      float v = 0.f;
      if ((unsigned)iy < 7u && (unsigned)ix < 7u)
        v = d2[((size_t)b * 128 + ic0 + ch) * 49 + iy * 7 + ix];
      s_in[ch * 108 + tr * 12 + tc] = v;
    }
  }
#pragma unroll
  for (int r = 0; r < 36; r++) {
    const int e = tid + 256 * r;
    const int o = e / 576, rem = e - o * 576;
    const int ch = rem / 9, tap = rem - ch * 9;
    s_w[ch * 144 + tap * 16 + o] =
        w[(size_t)(oc0 + o) * 1152 + (size_t)ic0 * 9 + rem];
  }
  __syncthreads();

  float acc = 0.f;
  for (int ic = 0; ic < 64; ic++) {
    const float* wrow = s_w + ic * 144 + oc;
    const float* irow = s_in + ic * 108 + 2 * y * 12 + 2 * x;
#pragma unroll
    for (int ky = 0; ky < 3; ky++)
#pragma unroll
      for (int kx = 0; kx < 3; kx++)
        acc = fmaf(wrow[(ky * 3 + kx) * 16], irow[ky * 12 + kx], acc);
  }
  p3[(((size_t)kc * NB + b) * 128 + oc0 + oc) * 16 + p] = acc;
}

// ---------------- fused tidy(1x1 convs) + NMS; d3 folded in from p3 ----------------
__global__ __launch_bounds__(256, 1)
void score_nms(const float* __restrict__ d1, const float* __restrict__ d2,
               const float* __restrict__ p3, const float* __restrict__ bd3,
               const float* __restrict__ w1, const float* __restrict__ b1,
               const float* __restrict__ w2, const float* __restrict__ b2,
               const float* __restrict__ w3, const float* __restrict__ b3,
               const int* __restrict__ anchors, float* __restrict__ score,
               float* __restrict__ out_idx, float* __restrict__ out_prob,
               float* __restrict__ sel) {
  __shared__ float s_in[32 * 200];     // t1 chunks; reused linearly for d2 (6272) / d3 (2048)
  __shared__ float s_w[21 * 128];      // w1(0..5), w2(6..11), w3(12..20)
  __shared__ float s_b[21];
  __shared__ float s_sc[NA];
  __shared__ float s_bx[NA * 4];
  __shared__ float r_s[256];
  __shared__ int r_i[256];
  const int b = blockIdx.x, tid = threadIdx.x;

  for (int i = tid; i < 768; i += 256) s_w[i] = w1[i];
  for (int i = tid; i < 768; i += 256) s_w[768 + i] = w2[i];
  for (int i = tid; i < 1152; i += 256) s_w[1536 + i] = w3[i];
  if (tid < 21) s_b[tid] = (tid < 6) ? b1[tid] : (tid < 12) ? b2[tid - 6] : b3[tid - 12];
  for (int i = tid; i < NA; i += 256) {
    s_bx[i * 4 + 0] = (float)anchors[i * 4 + 0];
    s_bx[i * 4 + 1] = (float)anchors[i * 4 + 1];
    s_bx[i * 4 + 2] = (float)anchors[i * 4 + 2];
    s_bx[i * 4 + 3] = (float)anchors[i * 4 + 3];
  }

  // ---- t1: 6 oc x 196 pos = 1176 scores, d1 staged in 4 chunks of 32 ic ----
  float acc[5] = {0.f, 0.f, 0.f, 0.f, 0.f};
  for (int chunk = 0; chunk < 4; chunk++) {
    __syncthreads();
    const float* src = d1 + ((size_t)b * 128 + chunk * 32) * 196;
#pragma unroll
    for (int r = 0; r < 7; r++) {
      int e = tid + 256 * r;
      if (e < 1568) {
        int ic = e / 49, f = e - ic * 49;
        *(float4*)(s_in + ic * 200 + f * 4) = ((const float4*)(src + (size_t)ic * 196))[f];
      }
    }
    __syncthreads();
#pragma unroll
    for (int k = 0; k < 5; k++) {
      int j = tid + 256 * k;
      if (j < 1176) {
        int oc = j / 196, p = j - oc * 196;
        const float* wr = s_w + oc * 128 + chunk * 32;
        float s = acc[k];
#pragma unroll
        for (int ic = 0; ic < 32; ic++) s = fmaf(wr[ic], s_in[ic * 200 + p], s);
        acc[k] = s;
      }
    }
  }
#pragma unroll
  for (int k = 0; k < 5; k++) {
    int j = tid + 256 * k;
    if (j < 1176) {
      int oc = j / 196;
      float s = acc[k] + s_b[oc];
      s_sc[j] = s;
      score[b * NA + j] = s;
    }
  }

  // ---- t2: 6 oc x 49 = 294 scores, d2[b] staged fully (linear) ----
  __syncthreads();
  {
    const float* src = d2 + (size_t)b * 6272;
#pragma unroll
    for (int r = 0; r < 7; r++) {
      int e = tid + 256 * r;
      if (e < 1568) *(float4*)(s_in + e * 4) = ((const float4*)src)[e];
    }
  }
  __syncthreads();
#pragma unroll
  for (int k = 0; k < 2; k++) {
    int jj = tid + 256 * k;
    if (jj < 294) {
      int oc = jj / 49, p = jj - oc * 49;
      const float* wr = s_w + 768 + oc * 128;
      float s = s_b[6 + oc];
#pragma unroll 8
      for (int ic = 0; ic < 128; ic++) s = fmaf(wr[ic], s_in[ic * 49 + p], s);
      s_sc[1176 + jj] = s;
      score[b * NA + 1176 + jj] = s;
    }
  }

  // ---- t3: 9 oc x 16 = 144 scores; d3 = relu(p3[0]+p3[1]+bd3) computed inline ----
  __syncthreads();
  {
    const float4* s0 = (const float4*)(p3 + (size_t)b * 2048);
    const float4* s1 = (const float4*)(p3 + 32768 + (size_t)b * 2048);
#pragma unroll
    for (int r = 0; r < 2; r++) {
      int e = tid + 256 * r;
      if (e < 512) {
        float4 a = s0[e], c = s1[e];
        float bb = bd3[e >> 2];
        float4 v;
        v.x = fmaxf(a.x + c.x + bb, 0.f);
        v.y = fmaxf(a.y + c.y + bb, 0.f);
        v.z = fmaxf(a.z + c.z + bb, 0.f);
        v.w = fmaxf(a.w + c.w + bb, 0.f);
        *(float4*)(s_in + e * 4) = v;
      }
    }
  }
  __syncthreads();
  if (tid < 144) {
    int oc = tid >> 4, p = tid & 15;
    const float* wr = s_w + 1536 + oc * 128;
    float s = s_b[12 + oc];
#pragma unroll 8
    for (int ic = 0; ic < 128; ic++) s = fmaf(wr[ic], s_in[ic * 16 + p], s);
    s_sc[1470 + tid] = s;
    score[b * NA + 1470 + tid] = s;
  }
  __syncthreads();

  // ---- NMS: TOPN=4, IoU>0.25 suppress ----
  for (int t = 0; t < 4; t++) {
    float bs = -__builtin_inff();
    int bi = NA;
    for (int i = tid; i < NA; i += 256) {
      float s = s_sc[i];
      if (s > bs || (s == bs && i < bi)) { bs = s; bi = i; }
    }
    r_s[tid] = bs; r_i[tid] = bi;
    __syncthreads();
    for (int off = 128; off > 0; off >>= 1) {
      if (tid < off) {
        float s2 = r_s[tid + off]; int i2 = r_i[tid + off];
        if (s2 > r_s[tid] || (s2 == r_s[tid] && i2 < r_i[tid])) { r_s[tid] = s2; r_i[tid] = i2; }
      }
      __syncthreads();
    }
    const int idx = r_i[0];
    const float by0 = s_bx[idx * 4 + 0], bx0 = s_bx[idx * 4 + 1];
    const float by1 = s_bx[idx * 4 + 2], bx1 = s_bx[idx * 4 + 3];
    if (tid == 0) {
      out_idx[b * 4 + t] = (float)idx;
      out_prob[b * 4 + t] = s_sc[idx];
      sel[(b * 4 + t) * 4 + 0] = by0;
      sel[(b * 4 + t) * 4 + 1] = bx0;
      sel[(b * 4 + t) * 4 + 2] = by1;
      sel[(b * 4 + t) * 4 + 3] = bx1;
    }
    __syncthreads();
    const float a = (by1 - by0) * (bx1 - bx0);
    for (int i = tid; i < NA; i += 256) {
      float cy0 = s_bx[i * 4 + 0], cx0 = s_bx[i * 4 + 1];
      float cy1 = s_bx[i * 4 + 2], cx1 = s_bx[i * 4 + 3];
      float yy0 = fmaxf(by0, cy0), xx0 = fmaxf(bx0, cx0);
      float yy1 = fminf(by1, cy1), xx1 = fminf(bx1, cx1);
      float inter = fmaxf(yy1 - yy0, 0.f) * fmaxf(xx1 - xx0, 0.f);
      float ar = (cy1 - cy0) * (cx1 - cx0);
      float iou = inter / (a + ar - inter);
      if (iou > 0.25f) s_sc[i] = -__builtin_inff();
    }
    __syncthreads();
  }
}

// ---------------- crop+bilinear resize to [16,4,3,224,224], 4 px/thread ----------------
__global__ void crop_kernel(const float* __restrict__ x, const float* __restrict__ sel,
                            float* __restrict__ out) {
  int i4 = blockIdx.x * 256 + threadIdx.x;
  const int total4 = NB * 4 * 3 * 224 * 56;
  if (i4 >= total4) return;
  int px0 = (i4 % 56) * 4;
  int t = i4 / 56;
  int py = t % 224; t /= 224;
  int ch = t % 3;  t /= 3;
  int n  = t % 4;
  int b  = t / 4;

  const float* bx = sel + (b * 4 + n) * 4;
  const float y0 = bx[0], x0 = bx[1], y1 = bx[2], x1 = bx[3];

  float ty = (float)py / 223.0f;
  float cy = y0 + (y1 - 1.0f - y0) * ty;
  float cyf = floorf(cy);
  int ylo = (int)cyf; ylo = ylo < 0 ? 0 : (ylo > 895 ? 895 : ylo);
  int yhi = ylo + 1 > 895 ? 895 : ylo + 1;
  float wy = cy - cyf;

  const float* img = x + ((size_t)b * 3 + ch) * 448 * 448;
  auto g = [&](int yy, int xx) -> float {
    yy -= 224; xx -= 224;
    if ((unsigned)yy < 448u && (unsigned)xx < 448u)
      return img[(size_t)yy * 448 + xx];
    return 0.f;
  };

  float4 res;
  float* rp = &res.x;
#pragma unroll
  for (int k = 0; k < 4; k++) {
    float tx = (float)(px0 + k) / 223.0f;
    float cx = x0 + (x1 - 1.0f - x0) * tx;
    float cxf = floorf(cx);
    int xlo = (int)cxf; xlo = xlo < 0 ? 0 : (xlo > 895 ? 895 : xlo);
    int xhi = xlo + 1 > 895 ? 895 : xlo + 1;
    float wx = cx - cxf;
    float v00 = g(ylo, xlo), v01 = g(ylo, xhi);
    float v10 = g(yhi, xlo), v11 = g(yhi, xhi);
    rp[k] = (1.f - wy) * ((1.f - wx) * v00 + wx * v01) +
            wy * ((1.f - wx) * v10 + wx * v11);
  }
  *(float4*)(out + (size_t)i4 * 4) = res;
}

extern "C" void kernel_launch(void* const* d_in, const int* in_sizes, int n_in,
                              void* d_out, int out_size, void* d_ws, size_t ws_size,
                              hipStream_t stream) {
  const float* x    = (const float*)d_in[0];
  const float* rpn  = (const float*)d_in[1];
  const int*   anc  = (const int*)d_in[2];
  const float* w_d1 = (const float*)d_in[3];
  const float* b_d1 = (const float*)d_in[4];
  const float* w_d2 = (const float*)d_in[5];
  const float* b_d2 = (const float*)d_in[6];
  const float* w_d3 = (const float*)d_in[7];
  const float* b_d3 = (const float*)d_in[8];
  const float* w_t1 = (const float*)d_in[9];
  const float* b_t1 = (const float*)d_in[10];
  const float* w_t2 = (const float*)d_in[11];
  const float* b_t2 = (const float*)d_in[12];
  const float* w_t3 = (const float*)d_in[13];
  const float* b_t3 = (const float*)d_in[14];

  float* out = (float*)d_out;
  float* ws = (float*)d_ws;

  float* d1  = ws;                        // 401408
  float* d2  = d1 + 401408;               // 100352
  float* d3  = d2 + 100352;               // 32768 (unused slot, kept for layout stability)
  float* sel = d3 + 32768;                // 256
  float* p2  = sel + 256;                 // 401408
  float* p3  = p2 + 401408;               // 65536
  unsigned short* wTh = (unsigned short*)(p3 + 65536);   // 2,359,296 ush
  unsigned short* wTl = wTh + 2359296;                   // 2,359,296 ush
  unsigned short* aTh = wTl + 2359296;                   // 6,422,528 ush
  unsigned short* aTl = aTh + 6422528;                   // 6,422,528 ush
  // total ws need: 39,134,208 B (identical to verified layout)

  float* score    = out;                  // 25824
  float* out_idx  = out + 25824;          // 64
  float* out_prob = out + 25888;          // 64
  float* parts    = out + 25952;          // 9,633,792 (final crop output)
  float* p1       = parts;                // 6,422,528 floats scratch; crop overwrites after

  prep<<<dim3(10240), dim3(256), 0, stream>>>(w_d1, rpn, wTh, wTl, aTh, aTl);
  conv1_mfma<<<dim3(256), dim3(256), 0, stream>>>(aTh, aTl, wTh, wTl, p1);
  conv1_finish_p<<<dim3(112), dim3(256), 0, stream>>>(p1, b_d1, d1);
  conv2_part<<<dim3(256), dim3(256), 0, stream>>>(d1, w_d2, p2);
  conv2_finish<<<dim3(392), dim3(256), 0, stream>>>(p2, b_d2, d2);
  conv3_part<<<dim3(256), dim3(256), 0, stream>>>(d2, w_d3, p3);
  score_nms<<<dim3(16), dim3(256), 0, stream>>>(d1, d2, p3, b_d3, w_t1, b_t1, w_t2, b_t2,
                                                w_t3, b_t3, anc, score, out_idx, out_prob, sel);
  crop_kernel<<<dim3(9408), dim3(256), 0, stream>>>(x, sel, parts);
}